// Round 1
// baseline (468.219 us; speedup 1.0000x reference)
//
#include <hip/hip_runtime.h>
#include <math.h>

#define BATCH 8192
#define HDIM  1024
#define KDIM  2048
#define NDIM  3072

typedef __attribute__((ext_vector_type(8))) short short8;
typedef __attribute__((ext_vector_type(4))) float floatx4;

__device__ __forceinline__ float b2f(unsigned short u) {
  union { unsigned int i; float f; } v; v.i = ((unsigned int)u) << 16; return v.f;
}
__device__ __forceinline__ unsigned short f2b(float f) {
  union { unsigned int i; float f; } v; v.f = f;
  unsigned int r = v.i + 0x7FFFu + ((v.i >> 16) & 1u);
  return (unsigned short)(r >> 16);
}
__device__ __forceinline__ float ldsel(const void* p, size_t i, int isbf) {
  return isbf ? b2f(((const unsigned short*)p)[i]) : ((const float*)p)[i];
}
__device__ __forceinline__ void stsel(void* p, size_t i, int isbf, float v) {
  if (isbf) ((unsigned short*)p)[i] = f2b(v);
  else ((float*)p)[i] = v;
}
__device__ __forceinline__ float sigf(float x) { return 1.0f / (1.0f + __expf(-x)); }

// async 16B global->LDS (CK-style addrspace casts)
__device__ __forceinline__ void gld16(const void* g, void* l) {
  auto gp = reinterpret_cast<__attribute__((address_space(1))) unsigned int*>(
      (unsigned long long)g);
  auto lp = reinterpret_cast<__attribute__((address_space(3))) unsigned int*>(
      (unsigned long long)l);
  __builtin_amdgcn_global_load_lds(gp, lp, 16, 0, 0);
}

// ---------------------------------------------------------------- dtype detect
// bf16 data: low 16 bits of each dword is a bf16 value of ~N(0,1) -> exponent
// field in [110,135] (or exact zero) nearly always. f32 data: low 16 bits are
// mantissa noise -> ~10% hit rate. Ballot over 64 words decides.
__global__ void k_detect(const unsigned int* __restrict__ x, int* __restrict__ flag) {
  unsigned int w = x[threadIdx.x];
  unsigned short lo = (unsigned short)(w & 0xFFFFu);
  int e = (lo >> 7) & 0xFF;
  bool ok = (e >= 110 && e <= 135) || ((lo & 0x7FFFu) == 0);
  unsigned long long m = __ballot(ok);
  if (threadIdx.x == 0) *flag = (__popcll(m) >= 48) ? 1 : 0;
}

// ---------------------------------------------------------------- weight pack
// WT[n][k] (bf16): n = gate*1024 + hid, k<1024 -> W_x[k][hid], k>=1024 -> W_h.
// 64x64 LDS tile transpose; mat = gate*2 + (0:x,1:h).
__global__ __launch_bounds__(256) void k_pack_w(
    const void* __restrict__ wxi, const void* __restrict__ whi,
    const void* __restrict__ wxc, const void* __restrict__ whc,
    const void* __restrict__ wxo, const void* __restrict__ who,
    unsigned short* __restrict__ WT, const int* __restrict__ flag) {
  const int isbf = *flag;
  const int bx = blockIdx.x;
  const int mat = bx >> 8;      // 0..5
  const int rem = bx & 255;
  const int ti = rem >> 4;      // k-tile
  const int tj = rem & 15;      // hid-tile
  const void* Ws[6] = {wxi, whi, wxc, whc, wxo, who};
  const void* W = Ws[mat];
  const int gt = mat >> 1;
  const int half = mat & 1;
  __shared__ float tbuf[64][65];
  const int tid = threadIdx.x;
  const int cr = tid >> 6;
  const int cc = tid & 63;
#pragma unroll
  for (int it = 0; it < 16; ++it) {
    int row = it * 4 + cr;  // k_local
    tbuf[row][cc] = ldsel(W, (size_t)(ti * 64 + row) * 1024 + tj * 64 + cc, isbf);
  }
  __syncthreads();
#pragma unroll
  for (int it = 0; it < 16; ++it) {
    int nl = it * 4 + cr;
    int n = gt * 1024 + tj * 64 + nl;
    int k = half * 1024 + ti * 64 + cc;
    WT[(size_t)n * KDIM + k] = f2b(tbuf[cc][nl]);
  }
}

// ------------------------------------------------- pack A=[x|h] + forget MLP
// One block per batch row. Thread t covers k in [8t, 8t+8): packs bf16 into A
// and accumulates the 16 W1 partial dots; shfl-xor wave reduce -> z1 -> z2 ->
// f = sigmoid(z2 @ W3 + b3) written to d_out section 2 (all MLP math in f32).
__global__ __launch_bounds__(256) void k_pack_a_mlp(
    const void* __restrict__ x, const void* __restrict__ h,
    const void* __restrict__ W1, const void* __restrict__ b1,
    const void* __restrict__ W2, const void* __restrict__ b2,
    const void* __restrict__ W3, const void* __restrict__ b3,
    unsigned short* __restrict__ A, void* __restrict__ out,
    const int* __restrict__ flag) {
  const int isbf = *flag;
  const int m = blockIdx.x;
  const int tid = threadIdx.x;
  __shared__ float wsum[4][16];
  __shared__ float z1s[16];
  __shared__ float z2s[8];
  const int k0 = tid * 8;
  const void* src = (tid < 128) ? x : h;
  const size_t soff = (size_t)m * 1024 + (size_t)((tid < 128) ? k0 : (k0 - 1024));
  float v[8];
  if (isbf) {
    const unsigned short* s = (const unsigned short*)src + soff;
    ushort4 a = *(const ushort4*)(s);
    ushort4 b = *(const ushort4*)(s + 4);
    v[0] = b2f(a.x); v[1] = b2f(a.y); v[2] = b2f(a.z); v[3] = b2f(a.w);
    v[4] = b2f(b.x); v[5] = b2f(b.y); v[6] = b2f(b.z); v[7] = b2f(b.w);
  } else {
    const float* s = (const float*)src + soff;
    float4 a = *(const float4*)(s);
    float4 b = *(const float4*)(s + 4);
    v[0] = a.x; v[1] = a.y; v[2] = a.z; v[3] = a.w;
    v[4] = b.x; v[5] = b.y; v[6] = b.z; v[7] = b.w;
  }
  short8 pk;
#pragma unroll
  for (int i = 0; i < 8; ++i) pk[i] = (short)f2b(v[i]);
  *(short8*)(A + (size_t)m * KDIM + k0) = pk;

  float acc[16];
#pragma unroll
  for (int j = 0; j < 16; ++j) acc[j] = 0.f;
  if (isbf) {
    const unsigned short* w1 = (const unsigned short*)W1;
#pragma unroll
    for (int i = 0; i < 8; ++i) {
      const size_t kb = (size_t)(k0 + i) * 16;
#pragma unroll
      for (int j = 0; j < 16; ++j) acc[j] += v[i] * b2f(w1[kb + j]);
    }
  } else {
    const float* w1 = (const float*)W1;
#pragma unroll
    for (int i = 0; i < 8; ++i) {
      const size_t kb = (size_t)(k0 + i) * 16;
#pragma unroll
      for (int j = 0; j < 16; ++j) acc[j] += v[i] * w1[kb + j];
    }
  }
#pragma unroll
  for (int off = 1; off < 64; off <<= 1) {
#pragma unroll
    for (int j = 0; j < 16; ++j) acc[j] += __shfl_xor(acc[j], off, 64);
  }
  if ((tid & 63) == 0) {
#pragma unroll
    for (int j = 0; j < 16; ++j) wsum[tid >> 6][j] = acc[j];
  }
  __syncthreads();
  if (tid < 16) {
    float s = wsum[0][tid] + wsum[1][tid] + wsum[2][tid] + wsum[3][tid] +
              ldsel(b1, (size_t)tid, isbf);
    z1s[tid] = fmaxf(s, 0.f);
  }
  __syncthreads();
  if (tid < 8) {
    float s = ldsel(b2, (size_t)tid, isbf);
#pragma unroll
    for (int i = 0; i < 16; ++i) s += z1s[i] * ldsel(W2, (size_t)i * 8 + tid, isbf);
    z2s[tid] = fmaxf(s, 0.f);
  }
  __syncthreads();
  float z2r[8];
#pragma unroll
  for (int j = 0; j < 8; ++j) z2r[j] = z2s[j];
  const size_t MH = (size_t)BATCH * HDIM;
#pragma unroll
  for (int it = 0; it < 4; ++it) {
    const int n = it * 256 + tid;
    float s;
    if (isbf) {
      const unsigned short* w3 = (const unsigned short*)W3;
      s = b2f(((const unsigned short*)b3)[n]);
#pragma unroll
      for (int j = 0; j < 8; ++j) s += z2r[j] * b2f(w3[(size_t)j * 1024 + n]);
    } else {
      const float* w3 = (const float*)W3;
      s = ((const float*)b3)[n];
#pragma unroll
      for (int j = 0; j < 8; ++j) s += z2r[j] * w3[(size_t)j * 1024 + n];
    }
    stsel(out, 2 * MH + (size_t)m * 1024 + n, isbf, sigf(s));
  }
}

// ---------------------------------------------------------------- main GEMM
// P[m][n] = sum_k A[m][k] * WT[n][k], bf16 in/out, f32 accumulate.
// 128x128 tile, BK=64, 4 waves (2x2), 4x4 frags of 16x16x32 MFMA per wave.
// LDS layout in 16B chunks: chunk(row,p) holds kc = p ^ (row&7) -> fragment
// ds_read_b128 spreads over all 32 banks (2-way max, free per m136), and the
// staging satisfies global_load_lds's base+lane*16 contiguity rule.
__global__ __launch_bounds__(256, 3) void k_gemm(
    const unsigned short* __restrict__ A,
    const unsigned short* __restrict__ WT,
    unsigned short* __restrict__ P) {
  __shared__ __align__(16) unsigned short lA[128 * 64];
  __shared__ __align__(16) unsigned short lB[128 * 64];
  const int tid = threadIdx.x;
  const int lane = tid & 63;
  const int wv = tid >> 6;
  const int wm = (wv >> 1) << 6;
  const int wn = (wv & 1) << 6;
  const int m0 = blockIdx.y << 7;
  const int n0 = blockIdx.x << 7;

  floatx4 acc[4][4];
  const floatx4 fzero = {0.f, 0.f, 0.f, 0.f};
#pragma unroll
  for (int i = 0; i < 4; ++i)
#pragma unroll
    for (int j = 0; j < 4; ++j) acc[i][j] = fzero;

  int rr[4], kk[4];
#pragma unroll
  for (int ps = 0; ps < 4; ++ps) {
    int chunk = ps * 256 + tid;
    rr[ps] = chunk >> 3;
    kk[ps] = (chunk & 7) ^ (rr[ps] & 7);
  }
  const int px0 = (lane >> 4) ^ (lane & 7);
  const int px1 = ((lane >> 4) + 4) ^ (lane & 7);
  const int rowA = wm + (lane & 15);
  const int rowB = wn + (lane & 15);

  for (int kt = 0; kt < KDIM / 64; ++kt) {
    const int k0 = kt * 64;
#pragma unroll
    for (int ps = 0; ps < 4; ++ps) {
      const int chunk = ps * 256 + tid;
      gld16(A + ((size_t)(m0 + rr[ps]) * KDIM + k0 + kk[ps] * 8), lA + chunk * 8);
      gld16(WT + ((size_t)(n0 + rr[ps]) * KDIM + k0 + kk[ps] * 8), lB + chunk * 8);
    }
    __syncthreads();
#pragma unroll
    for (int s = 0; s < 2; ++s) {
      const int px = s ? px1 : px0;
      short8 af[4], bfr[4];
#pragma unroll
      for (int i = 0; i < 4; ++i)
        af[i] = *(const short8*)(lA + ((((rowA + (i << 4)) << 3) + px) << 3));
#pragma unroll
      for (int i = 0; i < 4; ++i)
        bfr[i] = *(const short8*)(lB + ((((rowB + (i << 4)) << 3) + px) << 3));
#pragma unroll
      for (int mi = 0; mi < 4; ++mi)
#pragma unroll
        for (int ni = 0; ni < 4; ++ni)
          acc[mi][ni] = __builtin_amdgcn_mfma_f32_16x16x32_bf16(
              af[mi], bfr[ni], acc[mi][ni], 0, 0, 0);
    }
    __syncthreads();
  }
  // epilogue: C/D layout col=lane&15 (n), row=(lane>>4)*4+t (m)
  const int col = lane & 15;
  const int rq = (lane >> 4) << 2;
#pragma unroll
  for (int mi = 0; mi < 4; ++mi) {
#pragma unroll
    for (int ni = 0; ni < 4; ++ni) {
      const size_t n = (size_t)(n0 + wn + (ni << 4) + col);
#pragma unroll
      for (int t = 0; t < 4; ++t) {
        const size_t m = (size_t)(m0 + wm + (mi << 4) + rq + t);
        P[m * NDIM + n] = f2b(acc[mi][ni][t]);
      }
    }
  }
}

// ---------------------------------------------------------------- pointwise
__global__ __launch_bounds__(256) void k_pointwise(
    const unsigned short* __restrict__ P, const void* __restrict__ cin,
    const void* __restrict__ bi, const void* __restrict__ bc,
    const void* __restrict__ bo, void* __restrict__ out,
    const int* __restrict__ flag) {
  const int isbf = *flag;
  const size_t MH = (size_t)BATCH * HDIM;
  const size_t idx = ((size_t)blockIdx.x * 256 + threadIdx.x) * 4;
  const int n = (int)(idx & 1023);
  const size_t m = idx >> 10;
  const unsigned short* pr = P + m * NDIM + n;
  ushort4 ui = *(const ushort4*)(pr);
  ushort4 ug = *(const ushort4*)(pr + 1024);
  ushort4 uo = *(const ushort4*)(pr + 2048);
  float pi[4] = {b2f(ui.x), b2f(ui.y), b2f(ui.z), b2f(ui.w)};
  float pg[4] = {b2f(ug.x), b2f(ug.y), b2f(ug.z), b2f(ug.w)};
  float po[4] = {b2f(uo.x), b2f(uo.y), b2f(uo.z), b2f(uo.w)};
  float bif[4], bcf[4], bof[4], cf[4], ff[4];
  if (isbf) {
    ushort4 a = *(const ushort4*)((const unsigned short*)bi + n);
    ushort4 b = *(const ushort4*)((const unsigned short*)bc + n);
    ushort4 d = *(const ushort4*)((const unsigned short*)bo + n);
    ushort4 e = *(const ushort4*)((const unsigned short*)cin + idx);
    ushort4 g = *(const ushort4*)((const unsigned short*)out + 2 * MH + idx);
    bif[0]=b2f(a.x); bif[1]=b2f(a.y); bif[2]=b2f(a.z); bif[3]=b2f(a.w);
    bcf[0]=b2f(b.x); bcf[1]=b2f(b.y); bcf[2]=b2f(b.z); bcf[3]=b2f(b.w);
    bof[0]=b2f(d.x); bof[1]=b2f(d.y); bof[2]=b2f(d.z); bof[3]=b2f(d.w);
    cf[0]=b2f(e.x);  cf[1]=b2f(e.y);  cf[2]=b2f(e.z);  cf[3]=b2f(e.w);
    ff[0]=b2f(g.x);  ff[1]=b2f(g.y);  ff[2]=b2f(g.z);  ff[3]=b2f(g.w);
  } else {
    float4 a = *(const float4*)((const float*)bi + n);
    float4 b = *(const float4*)((const float*)bc + n);
    float4 d = *(const float4*)((const float*)bo + n);
    float4 e = *(const float4*)((const float*)cin + idx);
    float4 g = *(const float4*)((const float*)out + 2 * MH + idx);
    bif[0]=a.x; bif[1]=a.y; bif[2]=a.z; bif[3]=a.w;
    bcf[0]=b.x; bcf[1]=b.y; bcf[2]=b.z; bcf[3]=b.w;
    bof[0]=d.x; bof[1]=d.y; bof[2]=d.z; bof[3]=d.w;
    cf[0]=e.x;  cf[1]=e.y;  cf[2]=e.z;  cf[3]=e.w;
    ff[0]=g.x;  ff[1]=g.y;  ff[2]=g.z;  ff[3]=g.w;
  }
  float hn[4], cn[4];
#pragma unroll
  for (int t = 0; t < 4; ++t) {
    float I = sigf(pi[t] + bif[t]);
    float G = tanhf(pg[t] + bcf[t]);
    float O = sigf(po[t] + bof[t]);
    float C = ff[t] * cf[t] + I * G;
    cn[t] = C;
    hn[t] = O * tanhf(C);
  }
  if (isbf) {
    unsigned short* ob = (unsigned short*)out;
    *(ushort4*)(ob + idx) = make_ushort4(f2b(hn[0]), f2b(hn[1]), f2b(hn[2]), f2b(hn[3]));
    *(ushort4*)(ob + MH + idx) = make_ushort4(f2b(cn[0]), f2b(cn[1]), f2b(cn[2]), f2b(cn[3]));
  } else {
    float* ob = (float*)out;
    *(float4*)(ob + idx) = make_float4(hn[0], hn[1], hn[2], hn[3]);
    *(float4*)(ob + MH + idx) = make_float4(cn[0], cn[1], cn[2], cn[3]);
  }
}

extern "C" void kernel_launch(void* const* d_in, const int* in_sizes, int n_in,
                              void* d_out, int out_size, void* d_ws, size_t ws_size,
                              hipStream_t stream) {
  const void* x    = d_in[0];
  const void* h    = d_in[1];
  const void* c    = d_in[2];
  const void* W_hi = d_in[3];
  const void* W_xi = d_in[4];
  const void* b_i  = d_in[5];
  const void* W_hc = d_in[6];
  const void* W_xc = d_in[7];
  const void* b_c  = d_in[8];
  const void* W_ho = d_in[9];
  const void* W_xo = d_in[10];
  const void* b_o  = d_in[11];
  const void* W1   = d_in[12];
  const void* b1   = d_in[13];
  const void* W2   = d_in[14];
  const void* b2   = d_in[15];
  const void* W3   = d_in[16];
  const void* b3   = d_in[17];

  char* ws = (char*)d_ws;
  unsigned short* A  = (unsigned short*)ws;                                   // 32 MB
  unsigned short* WT = (unsigned short*)(ws + 33554432);                      // 12 MB
  unsigned short* P  = (unsigned short*)(ws + 33554432 + 12582912);           // 48 MB
  int* flag = (int*)(ws + 33554432 + 12582912 + 50331648);

  k_detect<<<dim3(1), dim3(64), 0, stream>>>((const unsigned int*)x, flag);
  k_pack_w<<<dim3(6 * 256), dim3(256), 0, stream>>>(W_xi, W_hi, W_xc, W_hc,
                                                    W_xo, W_ho, WT, flag);
  k_pack_a_mlp<<<dim3(BATCH), dim3(256), 0, stream>>>(x, h, W1, b1, W2, b2,
                                                      W3, b3, A, d_out, flag);
  k_gemm<<<dim3(NDIM / 128, BATCH / 128), dim3(256), 0, stream>>>(A, WT, P);
  k_pointwise<<<dim3(BATCH * HDIM / 1024), dim3(256), 0, stream>>>(
      P, c, b_i, b_c, b_o, d_out, flag);
}

// Round 2
// 383.536 us; speedup vs baseline: 1.2208x; 1.2208x over previous
//
#include <hip/hip_runtime.h>
#include <math.h>

#define BATCH 8192
#define HDIM  1024
#define KDIM  2048
#define NDIM  3072

typedef __attribute__((ext_vector_type(8))) short short8;
typedef __attribute__((ext_vector_type(4))) float floatx4;

__device__ __forceinline__ float b2f(unsigned short u) {
  union { unsigned int i; float f; } v; v.i = ((unsigned int)u) << 16; return v.f;
}
__device__ __forceinline__ unsigned short f2b(float f) {
  union { unsigned int i; float f; } v; v.f = f;
  unsigned int r = v.i + 0x7FFFu + ((v.i >> 16) & 1u);
  return (unsigned short)(r >> 16);
}
__device__ __forceinline__ float ldsel(const void* p, size_t i, int isbf) {
  return isbf ? b2f(((const unsigned short*)p)[i]) : ((const float*)p)[i];
}
__device__ __forceinline__ float sigf(float x) { return 1.0f / (1.0f + __expf(-x)); }
__device__ __forceinline__ float tanhfast(float x) {
  float a = __builtin_fabsf(x);
  float t = __expf(-2.f * a);
  float r = (1.f - t) / (1.f + t);
  return copysignf(r, x);
}

// async 16B global->LDS
__device__ __forceinline__ void gld16(const void* g, void* l) {
  auto gp = reinterpret_cast<__attribute__((address_space(1))) unsigned int*>(
      (unsigned long long)g);
  auto lp = reinterpret_cast<__attribute__((address_space(3))) unsigned int*>(
      (unsigned long long)l);
  __builtin_amdgcn_global_load_lds(gp, lp, 16, 0, 0);
}

// ---------------------------------------------------------------- dtype detect
__global__ void k_detect(const unsigned int* __restrict__ x, int* __restrict__ flag) {
  unsigned int w = x[threadIdx.x];
  unsigned short lo = (unsigned short)(w & 0xFFFFu);
  int e = (lo >> 7) & 0xFF;
  bool ok = (e >= 110 && e <= 135) || ((lo & 0x7FFFu) == 0);
  unsigned long long m = __ballot(ok);
  if (threadIdx.x == 0) *flag = (__popcll(m) >= 48) ? 1 : 0;
}

// ---------------------------------------------------------------- weight pack
// WT[n][k] bf16: n = gate*1024 + hid; k<1024 -> W_x[k][hid], k>=1024 -> W_h.
// 64x64 tiles, vectorized ushort8/float4 loads + short8 stores.
__global__ __launch_bounds__(256) void k_pack_w(
    const void* __restrict__ wxi, const void* __restrict__ whi,
    const void* __restrict__ wxc, const void* __restrict__ whc,
    const void* __restrict__ wxo, const void* __restrict__ who,
    unsigned short* __restrict__ WT, const int* __restrict__ flag) {
  const int isbf = *flag;
  const int bx = blockIdx.x;
  const int mat = bx >> 8;
  const int rem = bx & 255;
  const int ti = rem >> 4;      // k-tile
  const int tj = rem & 15;      // hid-tile
  const void* Ws[6] = {wxi, whi, wxc, whc, wxo, who};
  const void* W = Ws[mat];
  const int gt = mat >> 1;
  const int half = mat & 1;
  __shared__ float tbuf[64][65];
  const int t = threadIdx.x;
  const int rrow = t >> 3;       // 0..31
  const int c8 = (t & 7) * 8;
#pragma unroll
  for (int it = 0; it < 2; ++it) {
    int row = it * 32 + rrow;
    size_t off = (size_t)(ti * 64 + row) * 1024 + tj * 64 + c8;
    if (isbf) {
      const unsigned short* s = (const unsigned short*)W + off;
      ushort4 a = *(const ushort4*)(s);
      ushort4 b = *(const ushort4*)(s + 4);
      tbuf[row][c8+0]=b2f(a.x); tbuf[row][c8+1]=b2f(a.y);
      tbuf[row][c8+2]=b2f(a.z); tbuf[row][c8+3]=b2f(a.w);
      tbuf[row][c8+4]=b2f(b.x); tbuf[row][c8+5]=b2f(b.y);
      tbuf[row][c8+6]=b2f(b.z); tbuf[row][c8+7]=b2f(b.w);
    } else {
      const float* s = (const float*)W + off;
      float4 a = *(const float4*)(s);
      float4 b = *(const float4*)(s + 4);
      tbuf[row][c8+0]=a.x; tbuf[row][c8+1]=a.y; tbuf[row][c8+2]=a.z; tbuf[row][c8+3]=a.w;
      tbuf[row][c8+4]=b.x; tbuf[row][c8+5]=b.y; tbuf[row][c8+6]=b.z; tbuf[row][c8+7]=b.w;
    }
  }
  __syncthreads();
#pragma unroll
  for (int it = 0; it < 2; ++it) {
    int nl = it * 32 + rrow;
    int n = gt * 1024 + tj * 64 + nl;
    int kb = half * 1024 + ti * 64 + c8;
    short8 pk;
#pragma unroll
    for (int i = 0; i < 8; ++i) pk[i] = (short)f2b(tbuf[c8 + i][nl]);
    *(short8*)(WT + (size_t)n * KDIM + kb) = pk;
  }
}

// ------------------------------------------------- W1T pack: [16][2048] bf16
__global__ __launch_bounds__(256) void k_pack_small(
    const void* __restrict__ W1, unsigned short* __restrict__ W1T,
    const int* __restrict__ flag) {
  const int isbf = *flag;
  const int t = threadIdx.x;
  for (int k = t; k < 2048; k += 256) {
    unsigned short v[16];
    if (isbf) {
      const unsigned short* r = (const unsigned short*)W1 + (size_t)k * 16;
#pragma unroll
      for (int i = 0; i < 16; ++i) v[i] = r[i];
    } else {
      const float* r = (const float*)W1 + (size_t)k * 16;
#pragma unroll
      for (int i = 0; i < 16; ++i) v[i] = f2b(r[i]);
    }
#pragma unroll
    for (int nn = 0; nn < 16; ++nn) W1T[(size_t)nn * 2048 + k] = v[nn];
  }
}

// ------------------------------------------------- f32 fallback: pack A bf16
__global__ __launch_bounds__(256) void k_pack_a(
    const void* __restrict__ x, const void* __restrict__ h,
    unsigned short* __restrict__ A, const int* __restrict__ flag) {
  if (*flag) return;  // bf16 path: gemm reads x/h directly
  size_t idx = ((size_t)blockIdx.x * 256 + threadIdx.x) * 8;
  int k = (int)(idx & 2047);
  size_t m = idx >> 11;
  const float* s = (k < 1024) ? (const float*)x + m * 1024 + k
                              : (const float*)h + m * 1024 + (k - 1024);
  float4 a = *(const float4*)(s);
  float4 b = *(const float4*)(s + 4);
  short8 pk;
  pk[0]=(short)f2b(a.x); pk[1]=(short)f2b(a.y); pk[2]=(short)f2b(a.z); pk[3]=(short)f2b(a.w);
  pk[4]=(short)f2b(b.x); pk[5]=(short)f2b(b.y); pk[6]=(short)f2b(b.z); pk[7]=(short)f2b(b.w);
  *(short8*)(A + idx) = pk;
}

// ---------------------------------------------------------------- main GEMM
// P[m][n] = sum_k A[m][k]*WT[n][k]; A read directly from x|h (bf16) or packed A.
__global__ __launch_bounds__(256, 3) void k_gemm(
    const void* __restrict__ x, const void* __restrict__ h,
    const unsigned short* __restrict__ Apack,
    const unsigned short* __restrict__ WT,
    unsigned short* __restrict__ P, const int* __restrict__ flag) {
  const int isbf = *flag;
  const unsigned short* Ax = isbf ? (const unsigned short*)x : Apack;
  const unsigned short* Ah = isbf ? (const unsigned short*)h : (Apack + 1024);
  const int sA = isbf ? 1024 : 2048;
  __shared__ __align__(16) unsigned short lA[128 * 64];
  __shared__ __align__(16) unsigned short lB[128 * 64];
  const int tid = threadIdx.x;
  const int lane = tid & 63;
  const int wv = tid >> 6;
  const int wm = (wv >> 1) << 6;
  const int wn = (wv & 1) << 6;
  const int m0 = blockIdx.y << 7;
  const int n0 = blockIdx.x << 7;

  floatx4 acc[4][4];
  const floatx4 fzero = {0.f, 0.f, 0.f, 0.f};
#pragma unroll
  for (int i = 0; i < 4; ++i)
#pragma unroll
    for (int j = 0; j < 4; ++j) acc[i][j] = fzero;

  int rr[4], kk[4];
#pragma unroll
  for (int ps = 0; ps < 4; ++ps) {
    int chunk = ps * 256 + tid;
    rr[ps] = chunk >> 3;
    kk[ps] = (chunk & 7) ^ (rr[ps] & 7);
  }
  const int px0 = (lane >> 4) ^ (lane & 7);
  const int px1 = ((lane >> 4) + 4) ^ (lane & 7);
  const int rowA = wm + (lane & 15);
  const int rowB = wn + (lane & 15);

  for (int kt = 0; kt < KDIM / 64; ++kt) {
    const int k0 = kt * 64;
    const unsigned short* Abase = (k0 < 1024) ? (Ax + k0) : (Ah + (k0 - 1024));
#pragma unroll
    for (int ps = 0; ps < 4; ++ps) {
      const int chunk = ps * 256 + tid;
      gld16(Abase + (size_t)(m0 + rr[ps]) * sA + kk[ps] * 8, lA + chunk * 8);
      gld16(WT + ((size_t)(n0 + rr[ps]) * KDIM + k0 + kk[ps] * 8), lB + chunk * 8);
    }
    __syncthreads();
#pragma unroll
    for (int s = 0; s < 2; ++s) {
      const int px = s ? px1 : px0;
      short8 af[4], bfr[4];
#pragma unroll
      for (int i = 0; i < 4; ++i)
        af[i] = *(const short8*)(lA + ((((rowA + (i << 4)) << 3) + px) << 3));
#pragma unroll
      for (int i = 0; i < 4; ++i)
        bfr[i] = *(const short8*)(lB + ((((rowB + (i << 4)) << 3) + px) << 3));
#pragma unroll
      for (int mi = 0; mi < 4; ++mi)
#pragma unroll
        for (int ni = 0; ni < 4; ++ni)
          acc[mi][ni] = __builtin_amdgcn_mfma_f32_16x16x32_bf16(
              af[mi], bfr[ni], acc[mi][ni], 0, 0, 0);
    }
    __syncthreads();
  }
  const int col = lane & 15;
  const int rq = (lane >> 4) << 2;
#pragma unroll
  for (int mi = 0; mi < 4; ++mi) {
#pragma unroll
    for (int ni = 0; ni < 4; ++ni) {
      const size_t n = (size_t)(n0 + wn + (ni << 4) + col);
#pragma unroll
      for (int t = 0; t < 4; ++t) {
        const size_t m = (size_t)(m0 + wm + (mi << 4) + rq + t);
        P[m * NDIM + n] = f2b(acc[mi][ni][t]);
      }
    }
  }
}

// ---------------------------------------------------------------- z2 (MLP 1+2)
// One wave per 16 batch rows. z1 = relu(XH@W1+b1) via MFMA (K=2048),
// z2 = relu(z1@W2+b2) -> f32 [8192][8] in ws.
__global__ __launch_bounds__(64) void k_z2(
    const void* __restrict__ x, const void* __restrict__ h,
    const unsigned short* __restrict__ Apack,
    const unsigned short* __restrict__ W1T,
    const void* __restrict__ b1, const void* __restrict__ W2,
    const void* __restrict__ b2, float* __restrict__ z2,
    const int* __restrict__ flag) {
  const int isbf = *flag;
  const unsigned short* Ax = isbf ? (const unsigned short*)x : Apack;
  const unsigned short* Ah = isbf ? (const unsigned short*)h : (Apack + 1024);
  const int sA = isbf ? 1024 : 2048;
  const int lane = threadIdx.x;
  const int m0 = blockIdx.x * 16;
  const int q = lane >> 4;
  const int r = lane & 15;
  floatx4 acc = {0.f, 0.f, 0.f, 0.f};
  const unsigned short* arow0 = Ax + (size_t)(m0 + r) * sA;
  const unsigned short* arow1 = Ah + (size_t)(m0 + r) * sA;
  const unsigned short* brow = W1T + (size_t)r * 2048;
#pragma unroll 4
  for (int kt = 0; kt < 32; ++kt) {
    int k = kt * 32 + q * 8;
    short8 a = *(const short8*)(arow0 + k);
    short8 b = *(const short8*)(brow + k);
    acc = __builtin_amdgcn_mfma_f32_16x16x32_bf16(a, b, acc, 0, 0, 0);
  }
#pragma unroll 4
  for (int kt = 0; kt < 32; ++kt) {
    int k = kt * 32 + q * 8;
    short8 a = *(const short8*)(arow1 + k);
    short8 b = *(const short8*)(brow + 1024 + k);
    acc = __builtin_amdgcn_mfma_f32_16x16x32_bf16(a, b, acc, 0, 0, 0);
  }
  // C layout: col=lane&15 (n), row=q*4+t (m-local). z1 = relu(acc + b1[n]).
  __shared__ float z1s[16][17];
  float b1f = ldsel(b1, (size_t)r, isbf);
#pragma unroll
  for (int t = 0; t < 4; ++t) z1s[q * 4 + t][r] = fmaxf(acc[t] + b1f, 0.f);
  __syncthreads();
  const int row = lane >> 2;        // 0..15
  const int p2 = (lane & 3) * 2;    // 0,2,4,6
  float s0 = ldsel(b2, (size_t)p2, isbf);
  float s1 = ldsel(b2, (size_t)p2 + 1, isbf);
#pragma unroll
  for (int nn = 0; nn < 16; ++nn) {
    float z = z1s[row][nn];
    s0 += z * ldsel(W2, (size_t)nn * 8 + p2, isbf);
    s1 += z * ldsel(W2, (size_t)nn * 8 + p2 + 1, isbf);
  }
  float2 o = make_float2(fmaxf(s0, 0.f), fmaxf(s1, 0.f));
  *(float2*)(z2 + (size_t)(m0 + row) * 8 + p2) = o;
}

// ---------------------------------------------------------------- pointwise
// One block per batch row. Computes f = sigmoid(z2@W3+b3) inline.
__global__ __launch_bounds__(256) void k_pointwise(
    const unsigned short* __restrict__ P, const void* __restrict__ cin,
    const void* __restrict__ bi, const void* __restrict__ bc,
    const void* __restrict__ bo, const float* __restrict__ z2,
    const void* __restrict__ W3, const void* __restrict__ b3,
    void* __restrict__ out, const int* __restrict__ flag) {
  const int isbf = *flag;
  const size_t MH = (size_t)BATCH * HDIM;
  const size_t m = blockIdx.x;
  const int n = threadIdx.x * 4;
  const size_t idx = m * 1024 + n;
  const unsigned short* pr = P + m * NDIM + n;
  ushort4 ui = *(const ushort4*)(pr);
  ushort4 ug = *(const ushort4*)(pr + 1024);
  ushort4 uo = *(const ushort4*)(pr + 2048);
  float pi[4] = {b2f(ui.x), b2f(ui.y), b2f(ui.z), b2f(ui.w)};
  float pg[4] = {b2f(ug.x), b2f(ug.y), b2f(ug.z), b2f(ug.w)};
  float po[4] = {b2f(uo.x), b2f(uo.y), b2f(uo.z), b2f(uo.w)};
  // forget gate: f = sigmoid(z2[m] @ W3[:, n..n+3] + b3)
  float4 za = *(const float4*)(z2 + m * 8);
  float4 zb = *(const float4*)(z2 + m * 8 + 4);
  float zz[8] = {za.x, za.y, za.z, za.w, zb.x, zb.y, zb.z, zb.w};
  float f3[4];
  float bif[4], bcf[4], bof[4], cf[4];
  if (isbf) {
    ushort4 u3 = *(const ushort4*)((const unsigned short*)b3 + n);
    f3[0]=b2f(u3.x); f3[1]=b2f(u3.y); f3[2]=b2f(u3.z); f3[3]=b2f(u3.w);
#pragma unroll
    for (int j = 0; j < 8; ++j) {
      ushort4 w = *(const ushort4*)((const unsigned short*)W3 + (size_t)j * 1024 + n);
      f3[0] += zz[j]*b2f(w.x); f3[1] += zz[j]*b2f(w.y);
      f3[2] += zz[j]*b2f(w.z); f3[3] += zz[j]*b2f(w.w);
    }
    ushort4 a = *(const ushort4*)((const unsigned short*)bi + n);
    ushort4 b = *(const ushort4*)((const unsigned short*)bc + n);
    ushort4 d = *(const ushort4*)((const unsigned short*)bo + n);
    ushort4 e = *(const ushort4*)((const unsigned short*)cin + idx);
    bif[0]=b2f(a.x); bif[1]=b2f(a.y); bif[2]=b2f(a.z); bif[3]=b2f(a.w);
    bcf[0]=b2f(b.x); bcf[1]=b2f(b.y); bcf[2]=b2f(b.z); bcf[3]=b2f(b.w);
    bof[0]=b2f(d.x); bof[1]=b2f(d.y); bof[2]=b2f(d.z); bof[3]=b2f(d.w);
    cf[0]=b2f(e.x);  cf[1]=b2f(e.y);  cf[2]=b2f(e.z);  cf[3]=b2f(e.w);
  } else {
    float4 u3 = *(const float4*)((const float*)b3 + n);
    f3[0]=u3.x; f3[1]=u3.y; f3[2]=u3.z; f3[3]=u3.w;
#pragma unroll
    for (int j = 0; j < 8; ++j) {
      float4 w = *(const float4*)((const float*)W3 + (size_t)j * 1024 + n);
      f3[0] += zz[j]*w.x; f3[1] += zz[j]*w.y; f3[2] += zz[j]*w.z; f3[3] += zz[j]*w.w;
    }
    float4 a = *(const float4*)((const float*)bi + n);
    float4 b = *(const float4*)((const float*)bc + n);
    float4 d = *(const float4*)((const float*)bo + n);
    float4 e = *(const float4*)((const float*)cin + idx);
    bif[0]=a.x; bif[1]=a.y; bif[2]=a.z; bif[3]=a.w;
    bcf[0]=b.x; bcf[1]=b.y; bcf[2]=b.z; bcf[3]=b.w;
    bof[0]=d.x; bof[1]=d.y; bof[2]=d.z; bof[3]=d.w;
    cf[0]=e.x;  cf[1]=e.y;  cf[2]=e.z;  cf[3]=e.w;
  }
  float hn[4], cn[4], ff[4];
#pragma unroll
  for (int t = 0; t < 4; ++t) {
    float F = sigf(f3[t]);
    float I = sigf(pi[t] + bif[t]);
    float G = tanhfast(pg[t] + bcf[t]);
    float O = sigf(po[t] + bof[t]);
    float C = F * cf[t] + I * G;
    ff[t] = F;
    cn[t] = C;
    hn[t] = O * tanhfast(C);
  }
  if (isbf) {
    unsigned short* ob = (unsigned short*)out;
    *(ushort4*)(ob + idx) = make_ushort4(f2b(hn[0]), f2b(hn[1]), f2b(hn[2]), f2b(hn[3]));
    *(ushort4*)(ob + MH + idx) = make_ushort4(f2b(cn[0]), f2b(cn[1]), f2b(cn[2]), f2b(cn[3]));
    *(ushort4*)(ob + 2 * MH + idx) = make_ushort4(f2b(ff[0]), f2b(ff[1]), f2b(ff[2]), f2b(ff[3]));
  } else {
    float* ob = (float*)out;
    *(float4*)(ob + idx) = make_float4(hn[0], hn[1], hn[2], hn[3]);
    *(float4*)(ob + MH + idx) = make_float4(cn[0], cn[1], cn[2], cn[3]);
    *(float4*)(ob + 2 * MH + idx) = make_float4(ff[0], ff[1], ff[2], ff[3]);
  }
}

extern "C" void kernel_launch(void* const* d_in, const int* in_sizes, int n_in,
                              void* d_out, int out_size, void* d_ws, size_t ws_size,
                              hipStream_t stream) {
  const void* x    = d_in[0];
  const void* h    = d_in[1];
  const void* c    = d_in[2];
  const void* W_hi = d_in[3];
  const void* W_xi = d_in[4];
  const void* b_i  = d_in[5];
  const void* W_hc = d_in[6];
  const void* W_xc = d_in[7];
  const void* b_c  = d_in[8];
  const void* W_ho = d_in[9];
  const void* W_xo = d_in[10];
  const void* b_o  = d_in[11];
  const void* W1   = d_in[12];
  const void* b1   = d_in[13];
  const void* W2   = d_in[14];
  const void* b2   = d_in[15];
  const void* W3   = d_in[16];
  const void* b3   = d_in[17];

  char* ws = (char*)d_ws;
  unsigned short* A   = (unsigned short*)ws;                 // 33.5 MB (f32 path only)
  unsigned short* WT  = (unsigned short*)(ws + 33554432);    // 12.6 MB
  unsigned short* P   = (unsigned short*)(ws + 46137344);    // 50.3 MB
  float*          z2b = (float*)(ws + 96468992);             // 256 KB
  unsigned short* W1T = (unsigned short*)(ws + 96731136);    // 64 KB
  int*           flag = (int*)(ws + 96796672);

  k_detect<<<dim3(1), dim3(64), 0, stream>>>((const unsigned int*)x, flag);
  k_pack_w<<<dim3(6 * 256), dim3(256), 0, stream>>>(W_xi, W_hi, W_xc, W_hc,
                                                    W_xo, W_ho, WT, flag);
  k_pack_small<<<dim3(1), dim3(256), 0, stream>>>(W1, W1T, flag);
  k_pack_a<<<dim3(8192), dim3(256), 0, stream>>>(x, h, A, flag);
  k_gemm<<<dim3(NDIM / 128, BATCH / 128), dim3(256), 0, stream>>>(x, h, A, WT, P, flag);
  k_z2<<<dim3(BATCH / 16), dim3(64), 0, stream>>>(x, h, A, W1T, b1, W2, b2, z2b, flag);
  k_pointwise<<<dim3(BATCH), dim3(256), 0, stream>>>(P, c, b_i, b_c, b_o, z2b,
                                                     W3, b3, d_out, flag);
}